// Round 1
// baseline (79.605 us; speedup 1.0000x reference)
//
#include <hip/hip_runtime.h>
#include <math.h>

// LML layer: per row solve sum_j sigmoid(x_j + nu) = N (N=5), output sigmoid(x+nu).
// One wave (64 lanes) per row; 16 elements/lane in registers as E_j = exp(+x_j).
//
// u = exp(-nu):  sigmoid(x_j+nu) = E_j/(E_j+u).
//   g(u) = sum E/(E+u) - N is convex, strictly decreasing for u>0 (any data).
//   u0 = (sum E)/N  =>  g(u0) < 0; convexity => plain Newton globally
//   convergent (one left overshoot, then monotone from the left).
// Pass structure (3 passes over E, 50 trans ops/lane):
//   pass 1: load x, E=exp2(x*log2e), s0 = sum E   (no rcp needed)
//   pass 2: Newton iter A at u0 -> u1
//   pass 3: Newton iter B at u1: keep t=E/(E+u1), tr=t*r -> step delta,
//           and emit y = t - tr*delta (1st-order Taylor; 2nd-order err ~4e-8)
// Butterfly wave-reductions -> sums bitwise identical across lanes -> all
// control flow wave-uniform. No LDS, no barriers. NT stores (streaming out)
// via native clang vector type (HIP float4 is a class the builtin rejects).

constexpr int COLS = 1024;
constexpr int NTOP = 5;
constexpr int VPL  = COLS / 64;   // 16 values per lane
constexpr int WPB  = 4;           // waves (rows) per block

typedef float vfloat4 __attribute__((ext_vector_type(4)));

__device__ __forceinline__ float wave_sum(float v) {
#pragma unroll
    for (int m = 32; m >= 1; m >>= 1) v += __shfl_xor(v, m, 64);
    return v;
}
// Two interleaved reductions so the shfl latencies pipeline.
__device__ __forceinline__ void wave_sum2(float& a, float& b) {
#pragma unroll
    for (int m = 32; m >= 1; m >>= 1) {
        float ta = __shfl_xor(a, m, 64);
        float tb = __shfl_xor(b, m, 64);
        a += ta; b += tb;
    }
}

__global__ __launch_bounds__(WPB * 64) void lml_kernel(
        const float* __restrict__ x, float* __restrict__ y, int rows) {
    const int wave = threadIdx.x >> 6;
    const int lane = threadIdx.x & 63;
    const int row  = blockIdx.x * WPB + wave;
    if (row >= rows) return;

    const float* xr = x + (size_t)row * COLS;
    float*       yr = y + (size_t)row * COLS;

    constexpr float L2E = 1.4426950408889634f;   // log2(e)

    // ---- pass 1: load + exp, row-sum of E ----
    float E[VPL];
    float s0 = 0.0f;
#pragma unroll
    for (int w = 0; w < VPL / 4; ++w) {
        vfloat4 v = *reinterpret_cast<const vfloat4*>(xr + w * 256 + lane * 4);
        float e0 = __builtin_amdgcn_exp2f(v.x * L2E);
        float e1 = __builtin_amdgcn_exp2f(v.y * L2E);
        float e2 = __builtin_amdgcn_exp2f(v.z * L2E);
        float e3 = __builtin_amdgcn_exp2f(v.w * L2E);
        E[w * 4 + 0] = e0; E[w * 4 + 1] = e1;
        E[w * 4 + 2] = e2; E[w * 4 + 3] = e3;
        s0 += (e0 + e1) + (e2 + e3);
    }
    s0 = wave_sum(s0);                     // identical on all lanes

    float u = s0 * (1.0f / (float)NTOP);   // u0: g(u0) < 0 guaranteed

    // ---- pass 2: Newton iteration A ----
    {
        float G = 0.0f, H = 0.0f;
#pragma unroll
        for (int j = 0; j < VPL; ++j) {
            float r = __builtin_amdgcn_rcpf(E[j] + u);
            float t = E[j] * r;            // sigmoid value
            G += t;
            H = fmaf(t, r, H);             // -g'(u) = sum E/(E+u)^2
        }
        wave_sum2(G, H);
        u = fmaf(G - (float)NTOP, __builtin_amdgcn_rcpf(H), u);
        u = fmaxf(u, 1e-30f);              // paranoia, never hit for sane data
    }

    // ---- pass 3: Newton iteration B fused with epilogue (Taylor) ----
    float t[VPL], tr[VPL];
    float G = 0.0f, H = 0.0f;
#pragma unroll
    for (int j = 0; j < VPL; ++j) {
        float r  = __builtin_amdgcn_rcpf(E[j] + u);
        float tj = E[j] * r;
        float cj = tj * r;                 // dy/du magnitude = E/(E+u)^2
        t[j] = tj; tr[j] = cj;
        G += tj;
        H += cj;
    }
    wave_sum2(G, H);
    const float delta = (G - (float)NTOP) * __builtin_amdgcn_rcpf(H); // u step

#pragma unroll
    for (int w = 0; w < VPL / 4; ++w) {
        vfloat4 o;
        o.x = fmaf(-delta, tr[w * 4 + 0], t[w * 4 + 0]);
        o.y = fmaf(-delta, tr[w * 4 + 1], t[w * 4 + 1]);
        o.z = fmaf(-delta, tr[w * 4 + 2], t[w * 4 + 2]);
        o.w = fmaf(-delta, tr[w * 4 + 3], t[w * 4 + 3]);
        __builtin_nontemporal_store(o, reinterpret_cast<vfloat4*>(yr + w * 256 + lane * 4));
    }
}

extern "C" void kernel_launch(void* const* d_in, const int* in_sizes, int n_in,
                              void* d_out, int out_size, void* d_ws, size_t ws_size,
                              hipStream_t stream) {
    const float* x = (const float*)d_in[0];
    float* y = (float*)d_out;
    const int rows = in_sizes[0] / COLS;   // 8192
    const int grid = (rows + WPB - 1) / WPB;
    lml_kernel<<<grid, WPB * 64, 0, stream>>>(x, y, rows);
}